// Round 2
// baseline (552.187 us; speedup 1.0000x reference)
//
#include <hip/hip_runtime.h>

#define DIN 1024
#define DE  1024
#define SEQ 2048
#define NB  8

typedef __bf16 bf16x8 __attribute__((ext_vector_type(8)));
typedef float  f32x4  __attribute__((ext_vector_type(4)));
typedef unsigned short u16;
typedef u16 u16x8 __attribute__((ext_vector_type(8)));
typedef u16 u16x4 __attribute__((ext_vector_type(4)));

__device__ __forceinline__ u16 f2bf(float f) {
  unsigned u = __builtin_bit_cast(unsigned, f);
  return (u16)((u + 0x7FFFu + ((u >> 16) & 1u)) >> 16);
}
__device__ __forceinline__ float bf2f(u16 h) {
  return __builtin_bit_cast(float, (unsigned)h << 16);
}

// ---------------- convert fp32 -> bf16 (vectorized) ----------------
__global__ __launch_bounds__(256) void cvt_f32_bf16(const float* __restrict__ in,
                                                    u16* __restrict__ out, int n4) {
  int i = blockIdx.x * 256 + threadIdx.x;
  if (i >= n4) return;
  float4 v = ((const float4*)in)[i];
  u16x4 o;
  o[0] = f2bf(v.x); o[1] = f2bf(v.y); o[2] = f2bf(v.z); o[3] = f2bf(v.w);
  ((u16x4*)out)[i] = o;
}

// ---------------- transpose W [K=1024][N=1024] fp32 -> Wt [N][K] bf16 ----------------
__global__ __launch_bounds__(256) void transpose_w(const float* __restrict__ W,
                                                   u16* __restrict__ Wt) {
  __shared__ float t[32][33];
  const int tx = threadIdx.x, ty = threadIdx.y;
  const int bx = blockIdx.x * 32, by = blockIdx.y * 32;  // bx: N, by: K
#pragma unroll
  for (int i = 0; i < 4; ++i)
    t[ty + i * 8][tx] = W[(size_t)(by + ty + i * 8) * 1024 + bx + tx];
  __syncthreads();
#pragma unroll
  for (int i = 0; i < 4; ++i)
    Wt[(size_t)(bx + ty + i * 8) * 1024 + by + tx] = f2bf(t[tx][ty + i * 8]);
}

// ---------------- in-place row softmax on bf16 [rows][2048] ----------------
__global__ __launch_bounds__(256) void softmax_rows_bf16(u16* __restrict__ P) {
  const size_t row = blockIdx.x;
  u16* pr = P + row * 2048 + (size_t)threadIdx.x * 8;
  u16x8 v = *(const u16x8*)pr;
  float x[8];
#pragma unroll
  for (int j = 0; j < 8; ++j) x[j] = bf2f(v[j]);
  float m = x[0];
#pragma unroll
  for (int j = 1; j < 8; ++j) m = fmaxf(m, x[j]);
#pragma unroll
  for (int off = 32; off; off >>= 1) m = fmaxf(m, __shfl_xor(m, off));
  __shared__ float rm[4], rs[4];
  const int lane = threadIdx.x & 63, wid = threadIdx.x >> 6;
  if (lane == 0) rm[wid] = m;
  __syncthreads();
  m = fmaxf(fmaxf(rm[0], rm[1]), fmaxf(rm[2], rm[3]));
  float s = 0.f;
#pragma unroll
  for (int j = 0; j < 8; ++j) { x[j] = __expf(x[j] - m); s += x[j]; }
#pragma unroll
  for (int off = 32; off; off >>= 1) s += __shfl_xor(s, off);
  if (lane == 0) rs[wid] = s;
  __syncthreads();
  s = (rs[0] + rs[1]) + (rs[2] + rs[3]);
  const float inv = 1.f / s;
  u16x8 o;
#pragma unroll
  for (int j = 0; j < 8; ++j) o[j] = f2bf(x[j] * inv);
  *(u16x8*)pr = o;
}

// ---------------- generic bf16 MFMA GEMM: C = A[M,K] * Bt[N,K]^T (+bias) ----------------
// 128x128 tile, BK=64, 4 waves (2x2), 16x16x32 MFMA, XOR-swizzled LDS.
// OMODE: 0 = fp32 row-major, 1 = bf16 row-major, 2 = bf16 scattered as Vt[b][col][s]
template <int OMODE, bool HAS_BIAS>
__global__ __launch_bounds__(256, 2) void gemm_tn(
    const u16* __restrict__ A, const u16* __restrict__ Bt, void* __restrict__ Cv,
    const float* __restrict__ bias, int M, int N, int K,
    size_t sA, size_t sB, size_t sC, float scale) {
  __shared__ u16 lA[128 * 64];
  __shared__ u16 lB[128 * 64];
  const int tid = threadIdx.x, lane = tid & 63;
  const int wid = tid >> 6, wr = wid >> 1, wc = wid & 1;
  const int bx = blockIdx.x, by = blockIdx.y, bz = blockIdx.z;
  const u16* Ab = A + (size_t)bz * sA + (size_t)by * 128 * K;
  const u16* Bb = Bt + (size_t)bz * sB + (size_t)bx * 128 * K;
  f32x4 acc[4][4] = {};
  const int rfrag = lane & 15;
  const int koff = (lane >> 4) * 8;

  for (int k0 = 0; k0 < K; k0 += 64) {
    // stage A and B tiles [128 rows][64 cols] bf16 = 1024 16B-vectors each
#pragma unroll
    for (int h = 0; h < 2; ++h) {
      const u16* srcb = h ? Bb : Ab;
      u16* dstb = h ? lB : lA;
#pragma unroll
      for (int u2 = 0; u2 < 4; ++u2) {
        const int u = tid + u2 * 256;
        const int row = u >> 3, slot = u & 7;
        u16x8 v = *(const u16x8*)(srcb + (size_t)row * K + k0 + slot * 8);
        *(u16x8*)((char*)dstb + row * 128 + ((slot ^ (row & 7)) << 4)) = v;
      }
    }
    __syncthreads();
#pragma unroll
    for (int kk = 0; kk < 64; kk += 32) {
      bf16x8 af[4], bfr[4];
#pragma unroll
      for (int m = 0; m < 4; ++m) {
        const int r = wr * 64 + m * 16 + rfrag;
        const int slot = ((kk + koff) >> 3) ^ (r & 7);
        af[m] = *(const bf16x8*)((const char*)lA + r * 128 + (slot << 4));
      }
#pragma unroll
      for (int n = 0; n < 4; ++n) {
        const int r = wc * 64 + n * 16 + rfrag;
        const int slot = ((kk + koff) >> 3) ^ (r & 7);
        bfr[n] = *(const bf16x8*)((const char*)lB + r * 128 + (slot << 4));
      }
#pragma unroll
      for (int m = 0; m < 4; ++m)
#pragma unroll
        for (int n = 0; n < 4; ++n)
          acc[m][n] = __builtin_amdgcn_mfma_f32_16x16x32_bf16(af[m], bfr[n], acc[m][n], 0, 0, 0);
    }
    __syncthreads();
  }

  // epilogue: C layout col = lane&15, row = (lane>>4)*4 + reg
  const int rbase = by * 128 + wr * 64 + ((lane >> 4) << 2);
  const int cbase = bx * 128 + wc * 64 + (lane & 15);
#pragma unroll
  for (int m = 0; m < 4; ++m)
#pragma unroll
    for (int n = 0; n < 4; ++n) {
      const int col = cbase + n * 16;
      const float bval = HAS_BIAS ? bias[col] : 0.f;
#pragma unroll
      for (int r = 0; r < 4; ++r) {
        const int rowg = rbase + m * 16 + r;
        const float v = acc[m][n][r] * scale + bval;
        if (OMODE == 0)
          ((float*)Cv)[(size_t)bz * sC + (size_t)rowg * N + col] = v;
        else if (OMODE == 1)
          ((u16*)Cv)[(size_t)bz * sC + (size_t)rowg * N + col] = f2bf(v);
        else  // V-projection: write transposed Vt[b][col][s], b = rowg/2048
          ((u16*)Cv)[(size_t)(rowg >> 11) * ((size_t)DE * SEQ) +
                     (size_t)col * SEQ + (rowg & 2047)] = f2bf(v);
      }
    }
}

extern "C" void kernel_launch(void* const* d_in, const int* in_sizes, int n_in,
                              void* d_out, int out_size, void* d_ws, size_t ws_size,
                              hipStream_t stream) {
  const float* x  = (const float*)d_in[0];
  const float* Wq = (const float*)d_in[1];
  const float* bq = (const float*)d_in[2];
  const float* Wk = (const float*)d_in[3];
  const float* bk = (const float*)d_in[4];
  const float* Wv = (const float*)d_in[5];
  const float* bv = (const float*)d_in[6];
  const float* Wo = (const float*)d_in[7];
  const float* bo = (const float*)d_in[8];

  // workspace layout (bytes) — total 159,383,552 (~152 MB)
  const size_t NEED = 159383552;
  if (ws_size < NEED) return;  // fail cleanly (absmax) instead of page-faulting
  char* ws = (char*)d_ws;
  u16* x_bf = (u16*)(ws);                   // 33,554,432
  u16* q_bf = (u16*)(ws + 33554432);        // 33,554,432
  u16* k_bf = (u16*)(ws + 67108864);        // 33,554,432
  u16* vt   = (u16*)(ws + 100663296);       // 33,554,432  (V^T per batch [d][s])
  u16* wt   = (u16*)(ws + 134217728);       // 8,388,608   (4 x 2MB: q,k,v,o)
  u16* lgP  = (u16*)(ws + 142606336);       // 16,777,216  (2 batches of bf16 logits/P)
  u16* attn = x_bf;                         // alias; x_bf dead after V projection
  u16* wt_q = wt;
  u16* wt_k = wt + 1048576;
  u16* wt_v = wt + 2097152;
  u16* wt_o = wt + 3145728;

  dim3 tb(32, 8);
  const size_t sQ = (size_t)SEQ * DE;   // per-batch Q/K/attn stride
  const size_t sL = (size_t)SEQ * SEQ;  // per-batch logits stride

  // 1. x -> bf16
  cvt_f32_bf16<<<16384, 256, 0, stream>>>(x, x_bf, (NB * SEQ * DIN) / 4);
  // 2. weight transposes (fp32 -> bf16, [K,N] -> [N,K])
  transpose_w<<<dim3(32, 32), tb, 0, stream>>>(Wq, wt_q);
  transpose_w<<<dim3(32, 32), tb, 0, stream>>>(Wk, wt_k);
  transpose_w<<<dim3(32, 32), tb, 0, stream>>>(Wv, wt_v);
  transpose_w<<<dim3(32, 32), tb, 0, stream>>>(Wo, wt_o);
  // 3. QKV projections: [16384,1024] @ [1024,1024]^T + bias
  gemm_tn<1, true><<<dim3(8, 128, 1), 256, 0, stream>>>(x_bf, wt_q, q_bf, bq,
      16384, 1024, 1024, 0, 0, 0, 1.f);
  gemm_tn<1, true><<<dim3(8, 128, 1), 256, 0, stream>>>(x_bf, wt_k, k_bf, bk,
      16384, 1024, 1024, 0, 0, 0, 1.f);
  gemm_tn<2, true><<<dim3(8, 128, 1), 256, 0, stream>>>(x_bf, wt_v, vt, bv,
      16384, 1024, 1024, 0, 0, 0, 1.f);
  // 4. attention in 4 chunks of 2 batches (reuse 16 MB logits buffer)
  for (int c = 0; c < 4; ++c) {
    const u16* qb = q_bf + (size_t)(2 * c) * sQ;
    const u16* kb = k_bf + (size_t)(2 * c) * sQ;
    const u16* vb = vt + (size_t)(2 * c) * sQ;
    u16* ab = attn + (size_t)(2 * c) * sQ;
    // logits = Q @ K^T * (1/32) -> bf16
    gemm_tn<1, false><<<dim3(16, 16, 2), 256, 0, stream>>>(qb, kb, lgP, nullptr,
        2048, 2048, 1024, sQ, sQ, sL, 0.03125f);
    // in-place row softmax
    softmax_rows_bf16<<<2 * SEQ, 256, 0, stream>>>(lgP);
    // values = P @ Vt^T
    gemm_tn<1, false><<<dim3(8, 16, 2), 256, 0, stream>>>(lgP, vb, ab, nullptr,
        2048, 1024, 2048, sL, sQ, sQ, 1.f);
  }
  // 5. out = attn @ Wo + bo (fp32)
  gemm_tn<0, true><<<dim3(8, 128, 1), 256, 0, stream>>>(attn, wt_o, d_out, bo,
      16384, 1024, 1024, 0, 0, 0, 1.f);

  (void)in_sizes; (void)n_in; (void)out_size; (void)ws_size;
}

// Round 3
// 504.599 us; speedup vs baseline: 1.0943x; 1.0943x over previous
//
#include <hip/hip_runtime.h>

#define DIN 1024
#define DE  1024
#define SEQ 2048
#define NB  8

typedef __bf16 bf16x8 __attribute__((ext_vector_type(8)));
typedef float  f32x4  __attribute__((ext_vector_type(4)));
typedef unsigned short u16;
typedef u16 u16x8 __attribute__((ext_vector_type(8)));
typedef u16 u16x4 __attribute__((ext_vector_type(4)));

__device__ __forceinline__ u16 f2bf(float f) {
  unsigned u = __builtin_bit_cast(unsigned, f);
  return (u16)((u + 0x7FFFu + ((u >> 16) & 1u)) >> 16);
}
__device__ __forceinline__ float bf2f(u16 h) {
  return __builtin_bit_cast(float, (unsigned)h << 16);
}

typedef __attribute__((address_space(1))) const unsigned char g_u8;
typedef __attribute__((address_space(3))) unsigned char l_u8;
__device__ __forceinline__ void gload16(const void* g, void* l) {
  __builtin_amdgcn_global_load_lds((g_u8*)g, (l_u8*)l, 16, 0, 0);
}

// ---------------- convert fp32 -> bf16 (vectorized) ----------------
__global__ __launch_bounds__(256) void cvt_f32_bf16(const float* __restrict__ in,
                                                    u16* __restrict__ out, int n4) {
  int i = blockIdx.x * 256 + threadIdx.x;
  if (i >= n4) return;
  float4 v = ((const float4*)in)[i];
  u16x4 o;
  o[0] = f2bf(v.x); o[1] = f2bf(v.y); o[2] = f2bf(v.z); o[3] = f2bf(v.w);
  ((u16x4*)out)[i] = o;
}

// ---------------- transpose W [K=1024][N=1024] fp32 -> Wt [N][K] bf16 ----------------
__global__ __launch_bounds__(256) void transpose_w(const float* __restrict__ W,
                                                   u16* __restrict__ Wt) {
  __shared__ float t[32][33];
  const int tx = threadIdx.x, ty = threadIdx.y;
  const int bx = blockIdx.x * 32, by = blockIdx.y * 32;  // bx: N, by: K
#pragma unroll
  for (int i = 0; i < 4; ++i)
    t[ty + i * 8][tx] = W[(size_t)(by + ty + i * 8) * 1024 + bx + tx];
  __syncthreads();
#pragma unroll
  for (int i = 0; i < 4; ++i)
    Wt[(size_t)(bx + ty + i * 8) * 1024 + by + tx] = f2bf(t[tx][ty + i * 8]);
}

// ---------------- in-place row softmax on bf16 [rows][2048] ----------------
__global__ __launch_bounds__(256) void softmax_rows_bf16(u16* __restrict__ P) {
  const size_t row = blockIdx.x;
  u16* pr = P + row * 2048 + (size_t)threadIdx.x * 8;
  u16x8 v = *(const u16x8*)pr;
  float x[8];
#pragma unroll
  for (int j = 0; j < 8; ++j) x[j] = bf2f(v[j]);
  float m = x[0];
#pragma unroll
  for (int j = 1; j < 8; ++j) m = fmaxf(m, x[j]);
#pragma unroll
  for (int off = 32; off; off >>= 1) m = fmaxf(m, __shfl_xor(m, off));
  __shared__ float rm[4], rs[4];
  const int lane = threadIdx.x & 63, wid = threadIdx.x >> 6;
  if (lane == 0) rm[wid] = m;
  __syncthreads();
  m = fmaxf(fmaxf(rm[0], rm[1]), fmaxf(rm[2], rm[3]));
  float s = 0.f;
#pragma unroll
  for (int j = 0; j < 8; ++j) { x[j] = __expf(x[j] - m); s += x[j]; }
#pragma unroll
  for (int off = 32; off; off >>= 1) s += __shfl_xor(s, off);
  if (lane == 0) rs[wid] = s;
  __syncthreads();
  s = (rs[0] + rs[1]) + (rs[2] + rs[3]);
  const float inv = 1.f / s;
  u16x8 o;
#pragma unroll
  for (int j = 0; j < 8; ++j) o[j] = f2bf(x[j] * inv);
  *(u16x8*)pr = o;
}

// ---------------- bf16 MFMA GEMM: C = A[M,K] * Bt[N,K]^T (+bias) ----------------
// m97 structure: 128x128 tile, BK=64, 4 waves, global_load_lds width-16 staging
// with pre-swizzled source (linear LDS dest + swizzled reads), XCD-aware blockIdx.
// OMODE: 0 = fp32 row-major, 1 = bf16 row-major, 2 = bf16 scattered as Vt[b][col][s]
template <int OMODE, bool HAS_BIAS>
__global__ __launch_bounds__(256) void gemm_tn(
    const u16* __restrict__ A, const u16* __restrict__ Bt, void* __restrict__ Cv,
    const float* __restrict__ bias, int M, int N, int K,
    size_t sA, size_t sB, size_t sC, float scale) {
  __shared__ u16 lA[128 * 64];
  __shared__ u16 lB[128 * 64];
  const int tid = threadIdx.x, lane = tid & 63;
  const int wid = tid >> 6, wr = wid >> 1, wc = wid & 1;

  // bijective XCD-aware block remap (m204)
  const int gx = gridDim.x, gy = gridDim.y;
  int lin = blockIdx.x + gx * (blockIdx.y + gy * blockIdx.z);
  const int nwg = gx * gy * (int)gridDim.z;
  const int q = nwg >> 3, r8 = nwg & 7;
  const int xcd = lin & 7, idx = lin >> 3;
  lin = (xcd < r8 ? xcd * (q + 1) : r8 * (q + 1) + (xcd - r8) * q) + idx;
  const int bz = lin / (gx * gy);
  const int rem = lin - bz * (gx * gy);
  const int by = rem / gx, bx = rem - (rem / gx) * gx;

  const char* Ab = (const char*)(A + (size_t)bz * sA + (size_t)by * 128 * K);
  const char* Bb = (const char*)(Bt + (size_t)bz * sB + (size_t)bx * 128 * K);

  // staging map: wave call j covers LDS rows (wid*4+j)*8..+8 (1 KB linear chunk).
  // lane l -> row +(l>>3), phys slot l&7; source slot pre-swizzled = (l&7)^(l>>3)
  const int srow = lane >> 3;
  const int gslot = (lane & 7) ^ srow;
  size_t off[4];
  char* ldsA[4];
  char* ldsB[4];
#pragma unroll
  for (int j = 0; j < 4; ++j) {
    const int row = (wid * 4 + j) * 8 + srow;
    off[j] = (size_t)row * K * 2 + (size_t)gslot * 16;
    ldsA[j] = (char*)lA + (wid * 4 + j) * 1024;
    ldsB[j] = (char*)lB + (wid * 4 + j) * 1024;
  }

  f32x4 acc[4][4] = {};
  const int rfrag = lane & 15;
  const int koff = (lane >> 4) * 8;

  for (int k0 = 0; k0 < K; k0 += 64) {
    // async stage A and B tiles (8 x global_load_lds_dwordx4 per thread)
#pragma unroll
    for (int j = 0; j < 4; ++j) {
      gload16(Ab + off[j], ldsA[j]);
      gload16(Bb + off[j], ldsB[j]);
      off[j] += 128;  // advance 64 bf16 along K
    }
    __syncthreads();  // drains vmcnt(0): staged data visible to all waves
#pragma unroll
    for (int kk = 0; kk < 64; kk += 32) {
      bf16x8 af[4], bfr[4];
#pragma unroll
      for (int m = 0; m < 4; ++m) {
        const int r = wr * 64 + m * 16 + rfrag;
        const int slot = ((kk + koff) >> 3) ^ (r & 7);
        af[m] = *(const bf16x8*)((const char*)lA + r * 128 + (slot << 4));
      }
#pragma unroll
      for (int n = 0; n < 4; ++n) {
        const int r = wc * 64 + n * 16 + rfrag;
        const int slot = ((kk + koff) >> 3) ^ (r & 7);
        bfr[n] = *(const bf16x8*)((const char*)lB + r * 128 + (slot << 4));
      }
#pragma unroll
      for (int m = 0; m < 4; ++m)
#pragma unroll
        for (int n = 0; n < 4; ++n)
          acc[m][n] = __builtin_amdgcn_mfma_f32_16x16x32_bf16(af[m], bfr[n], acc[m][n], 0, 0, 0);
    }
    __syncthreads();  // all reads done before next tile's stage overwrites
  }

  // epilogue: C layout col = lane&15, row = (lane>>4)*4 + reg
  const int rbase = by * 128 + wr * 64 + ((lane >> 4) << 2);
  const int cbase = bx * 128 + wc * 64 + (lane & 15);
#pragma unroll
  for (int m = 0; m < 4; ++m)
#pragma unroll
    for (int n = 0; n < 4; ++n) {
      const int col = cbase + n * 16;
      const float bval = HAS_BIAS ? bias[col] : 0.f;
#pragma unroll
      for (int r = 0; r < 4; ++r) {
        const int rowg = rbase + m * 16 + r;
        const float v = acc[m][n][r] * scale + bval;
        if (OMODE == 0)
          ((float*)Cv)[(size_t)bz * sC + (size_t)rowg * N + col] = v;
        else if (OMODE == 1)
          ((u16*)Cv)[(size_t)bz * sC + (size_t)rowg * N + col] = f2bf(v);
        else  // V-projection: write transposed Vt[b][col][s], b = rowg/2048
          ((u16*)Cv)[(size_t)(rowg >> 11) * ((size_t)DE * SEQ) +
                     (size_t)col * SEQ + (rowg & 2047)] = f2bf(v);
      }
    }
}

extern "C" void kernel_launch(void* const* d_in, const int* in_sizes, int n_in,
                              void* d_out, int out_size, void* d_ws, size_t ws_size,
                              hipStream_t stream) {
  const float* x  = (const float*)d_in[0];
  const float* Wq = (const float*)d_in[1];
  const float* bq = (const float*)d_in[2];
  const float* Wk = (const float*)d_in[3];
  const float* bk = (const float*)d_in[4];
  const float* Wv = (const float*)d_in[5];
  const float* bv = (const float*)d_in[6];
  const float* Wo = (const float*)d_in[7];
  const float* bo = (const float*)d_in[8];

  // workspace layout (bytes) — total 159,383,552 (~152 MB)
  const size_t NEED = 159383552;
  if (ws_size < NEED) return;  // fail cleanly instead of page-faulting
  char* ws = (char*)d_ws;
  u16* x_bf = (u16*)(ws);                   // 33,554,432
  u16* q_bf = (u16*)(ws + 33554432);        // 33,554,432
  u16* k_bf = (u16*)(ws + 67108864);        // 33,554,432
  u16* vt   = (u16*)(ws + 100663296);       // 33,554,432  (V^T per batch [d][s])
  u16* wt   = (u16*)(ws + 134217728);       // 8,388,608   (4 x 2MB: q,k,v,o)
  u16* lgP  = (u16*)(ws + 142606336);       // 16,777,216  (2 batches of bf16 logits/P)
  u16* attn = x_bf;                         // alias; x_bf dead after V projection
  u16* wt_q = wt;
  u16* wt_k = wt + 1048576;
  u16* wt_v = wt + 2097152;
  u16* wt_o = wt + 3145728;

  dim3 tb(32, 8);
  const size_t sQ = (size_t)SEQ * DE;   // per-batch Q/K/attn stride
  const size_t sL = (size_t)SEQ * SEQ;  // per-batch logits stride

  // 1. x -> bf16
  cvt_f32_bf16<<<16384, 256, 0, stream>>>(x, x_bf, (NB * SEQ * DIN) / 4);
  // 2. weight transposes (fp32 -> bf16, [K,N] -> [N,K])
  transpose_w<<<dim3(32, 32), tb, 0, stream>>>(Wq, wt_q);
  transpose_w<<<dim3(32, 32), tb, 0, stream>>>(Wk, wt_k);
  transpose_w<<<dim3(32, 32), tb, 0, stream>>>(Wv, wt_v);
  transpose_w<<<dim3(32, 32), tb, 0, stream>>>(Wo, wt_o);
  // 3. QKV projections: [16384,1024] @ [1024,1024]^T + bias
  gemm_tn<1, true><<<dim3(8, 128, 1), 256, 0, stream>>>(x_bf, wt_q, q_bf, bq,
      16384, 1024, 1024, 0, 0, 0, 1.f);
  gemm_tn<1, true><<<dim3(8, 128, 1), 256, 0, stream>>>(x_bf, wt_k, k_bf, bk,
      16384, 1024, 1024, 0, 0, 0, 1.f);
  gemm_tn<2, true><<<dim3(8, 128, 1), 256, 0, stream>>>(x_bf, wt_v, vt, bv,
      16384, 1024, 1024, 0, 0, 0, 1.f);
  // 4. attention in 4 chunks of 2 batches (reuse 16 MB logits buffer)
  for (int c = 0; c < 4; ++c) {
    const u16* qb = q_bf + (size_t)(2 * c) * sQ;
    const u16* kb = k_bf + (size_t)(2 * c) * sQ;
    const u16* vb = vt + (size_t)(2 * c) * sQ;
    u16* ab = attn + (size_t)(2 * c) * sQ;
    // logits = Q @ K^T * (1/32) -> bf16
    gemm_tn<1, false><<<dim3(16, 16, 2), 256, 0, stream>>>(qb, kb, lgP, nullptr,
        2048, 2048, 1024, sQ, sQ, sL, 0.03125f);
    // in-place row softmax
    softmax_rows_bf16<<<2 * SEQ, 256, 0, stream>>>(lgP);
    // values = P @ Vt^T
    gemm_tn<1, false><<<dim3(8, 16, 2), 256, 0, stream>>>(lgP, vb, ab, nullptr,
        2048, 1024, 2048, sL, sQ, sQ, 1.f);
  }
  // 5. out = attn @ Wo + bo (fp32)
  gemm_tn<0, true><<<dim3(8, 128, 1), 256, 0, stream>>>(attn, wt_o, d_out, bo,
      16384, 1024, 1024, 0, 0, 0, 1.f);

  (void)in_sizes; (void)n_in; (void)out_size; (void)ws_size;
}

// Round 4
// 478.923 us; speedup vs baseline: 1.1530x; 1.0536x over previous
//
#include <hip/hip_runtime.h>

#define DIN 1024
#define DE  1024
#define SEQ 2048
#define NB  8

typedef __bf16 bf16x8 __attribute__((ext_vector_type(8)));
typedef float  f32x4  __attribute__((ext_vector_type(4)));
typedef unsigned short u16;
typedef u16 u16x8 __attribute__((ext_vector_type(8)));
typedef u16 u16x4 __attribute__((ext_vector_type(4)));

__device__ __forceinline__ u16 f2bf(float f) {
  unsigned u = __builtin_bit_cast(unsigned, f);
  return (u16)((u + 0x7FFFu + ((u >> 16) & 1u)) >> 16);
}
__device__ __forceinline__ float bf2f(u16 h) {
  return __builtin_bit_cast(float, (unsigned)h << 16);
}

typedef __attribute__((address_space(1))) const unsigned char g_u8;
typedef __attribute__((address_space(3))) unsigned char l_u8;
__device__ __forceinline__ void gload16(const void* g, void* l) {
  __builtin_amdgcn_global_load_lds((g_u8*)g, (l_u8*)l, 16, 0, 0);
}

// ---------------- convert fp32 -> bf16 (vectorized) ----------------
__global__ __launch_bounds__(256) void cvt_f32_bf16(const float* __restrict__ in,
                                                    u16* __restrict__ out, int n4) {
  int i = blockIdx.x * 256 + threadIdx.x;
  if (i >= n4) return;
  float4 v = ((const float4*)in)[i];
  u16x4 o;
  o[0] = f2bf(v.x); o[1] = f2bf(v.y); o[2] = f2bf(v.z); o[3] = f2bf(v.w);
  ((u16x4*)out)[i] = o;
}

// ---------------- transpose W [K=1024][N=1024] fp32 -> Wt [N][K] bf16 ----------------
__global__ __launch_bounds__(256) void transpose_w(const float* __restrict__ W,
                                                   u16* __restrict__ Wt) {
  __shared__ float t[32][33];
  const int tx = threadIdx.x, ty = threadIdx.y;
  const int bx = blockIdx.x * 32, by = blockIdx.y * 32;  // bx: N, by: K
#pragma unroll
  for (int i = 0; i < 4; ++i)
    t[ty + i * 8][tx] = W[(size_t)(by + ty + i * 8) * 1024 + bx + tx];
  __syncthreads();
#pragma unroll
  for (int i = 0; i < 4; ++i)
    Wt[(size_t)(bx + ty + i * 8) * 1024 + by + tx] = f2bf(t[tx][ty + i * 8]);
}

// ---------------- in-place row softmax on bf16 [rows][2048] ----------------
__global__ __launch_bounds__(256) void softmax_rows_bf16(u16* __restrict__ P) {
  const size_t row = blockIdx.x;
  u16* pr = P + row * 2048 + (size_t)threadIdx.x * 8;
  u16x8 v = *(const u16x8*)pr;
  float x[8];
#pragma unroll
  for (int j = 0; j < 8; ++j) x[j] = bf2f(v[j]);
  float m = x[0];
#pragma unroll
  for (int j = 1; j < 8; ++j) m = fmaxf(m, x[j]);
#pragma unroll
  for (int off = 32; off; off >>= 1) m = fmaxf(m, __shfl_xor(m, off));
  __shared__ float rm[4], rs[4];
  const int lane = threadIdx.x & 63, wid = threadIdx.x >> 6;
  if (lane == 0) rm[wid] = m;
  __syncthreads();
  m = fmaxf(fmaxf(rm[0], rm[1]), fmaxf(rm[2], rm[3]));
  float s = 0.f;
#pragma unroll
  for (int j = 0; j < 8; ++j) { x[j] = __expf(x[j] - m); s += x[j]; }
#pragma unroll
  for (int off = 32; off; off >>= 1) s += __shfl_xor(s, off);
  if (lane == 0) rs[wid] = s;
  __syncthreads();
  s = (rs[0] + rs[1]) + (rs[2] + rs[3]);
  const float inv = 1.f / s;
  u16x8 o;
#pragma unroll
  for (int j = 0; j < 8; ++j) o[j] = f2bf(x[j] * inv);
  *(u16x8*)pr = o;
}

// ============ 8-phase-style deep-pipelined GEMM: C = A[M,K] * Bt[N,K]^T ============
// BM=BN=256, BK=32, quad-buffered LDS (128 KiB), 8 waves (2Mx4N), counted vmcnt(8),
// XOR-swizzled LDS via pre-swizzled global source, setprio around MFMA clusters.
// Race-freedom: tile t reads buf[t&3]; stage of tile t+3 (issued during tile t,
// pinned by sched_barrier at boundaries) writes buf[(t+3)&3]=buf[(t-1)&3], whose
// last reader (tile t-1) finished before the boundary barrier. vmcnt(8)+barrier
// before tile t+1 guarantees all waves' t+1 loads landed (4 loads/wave/tile).
// OMODE: 0 = fp32 row-major, 1 = bf16 row-major, 2 = bf16 scattered as Vt[b][col][s]
template <int OMODE, bool HAS_BIAS>
__global__ __launch_bounds__(512, 2) void gemm8p(
    const u16* __restrict__ A, const u16* __restrict__ Bt, void* __restrict__ Cv,
    const float* __restrict__ bias, int M, int N, int K, float scale) {
  __shared__ __align__(16) char lds8[131072];
  const int tid = threadIdx.x, lane = tid & 63, wid = tid >> 6;
  const int wm = wid >> 2, wn = wid & 3;

  // bijective XCD-aware block remap (m204)
  const int gx = gridDim.x;
  int lin = blockIdx.x + gx * blockIdx.y;
  const int nwg = gx * gridDim.y;
  const int q = nwg >> 3, r8 = nwg & 7;
  const int xcd = lin & 7, idx = lin >> 3;
  lin = (xcd < r8 ? xcd * (q + 1) : r8 * (q + 1) + (xcd - r8) * q) + idx;
  const int by = lin / gx, bx = lin - (lin / gx) * gx;

  const char* Ag = (const char*)(A + (size_t)by * 256 * K);
  const char* Bg = (const char*)(Bt + (size_t)bx * 256 * K);

  // staging: thread u handles row i*128+(u>>2), phys slot u&3; source slot
  // pre-swizzled: logical = (u&3) ^ ((u>>2)&3)  (involution with read swizzle)
  const int srow = tid >> 2;
  const int lslot = (tid & 3) ^ (srow & 3);
  const size_t Kb = (size_t)K * 2;
  const char* ga0 = Ag + (size_t)srow * Kb + lslot * 16;
  const char* ga1 = Ag + (size_t)(128 + srow) * Kb + lslot * 16;
  const char* gb0 = Bg + (size_t)srow * Kb + lslot * 16;
  const char* gb1 = Bg + (size_t)(128 + srow) * Kb + lslot * 16;
  const int ldsw = wid * 1024;  // wave's 1KB chunk within each 8KB issue region

  // fragment read addressing: row r at byte r*64, phys slot = (lane>>4)^(r&3)
  const int lane15 = lane & 15;
  const int xslot = ((lane >> 4) ^ (lane15 & 3)) << 4;
  const int aoff = wm * 8192 + lane15 * 64 + xslot;           // A region offset
  const int boff = 16384 + wn * 4096 + lane15 * 64 + xslot;   // B region offset

  f32x4 acc[8][4] = {};
  const int NT = K >> 5;

  // prologue: stage tiles 0..2 (12 loads/wave), wait tile 0 (vmcnt 8)
#pragma unroll
  for (int pt = 0; pt < 3; ++pt) {
    char* db = lds8 + pt * 32768 + ldsw;
    gload16(ga0, db);
    gload16(ga1, db + 8192);
    gload16(gb0, db + 16384);
    gload16(gb1, db + 24576);
    ga0 += 64; ga1 += 64; gb0 += 64; gb1 += 64;
  }
  asm volatile("s_waitcnt vmcnt(8)" ::: "memory");
  __builtin_amdgcn_s_barrier();
  __builtin_amdgcn_sched_barrier(0);

  for (int t = 0; t < NT; ++t) {
    const char* base = lds8 + (t & 3) * 32768;
    char* dst = lds8 + ((t + 3) & 3) * 32768 + ldsw;
    const bool st = (t + 3) < NT;
    bf16x8 af[4], bfr[4];
    // ---- phase 0: B frags + A m-half 0, stage A of tile t+3, 16 MFMA ----
#pragma unroll
    for (int n = 0; n < 4; ++n) bfr[n] = *(const bf16x8*)(base + boff + n * 1024);
#pragma unroll
    for (int m = 0; m < 4; ++m) af[m] = *(const bf16x8*)(base + aoff + m * 1024);
    if (st) { gload16(ga0, dst); gload16(ga1, dst + 8192); }
    __builtin_amdgcn_s_setprio(1);
#pragma unroll
    for (int m = 0; m < 4; ++m)
#pragma unroll
      for (int n = 0; n < 4; ++n)
        acc[m][n] = __builtin_amdgcn_mfma_f32_16x16x32_bf16(af[m], bfr[n], acc[m][n], 0, 0, 0);
    __builtin_amdgcn_s_setprio(0);
    __builtin_amdgcn_s_barrier();
    // ---- phase 1: A m-half 1, stage B of tile t+3, 16 MFMA ----
#pragma unroll
    for (int m = 0; m < 4; ++m) af[m] = *(const bf16x8*)(base + aoff + 4096 + m * 1024);
    if (st) {
      gload16(gb0, dst + 16384); gload16(gb1, dst + 24576);
      ga0 += 64; ga1 += 64; gb0 += 64; gb1 += 64;
    }
    __builtin_amdgcn_s_setprio(1);
#pragma unroll
    for (int m = 0; m < 4; ++m)
#pragma unroll
      for (int n = 0; n < 4; ++n)
        acc[4 + m][n] = __builtin_amdgcn_mfma_f32_16x16x32_bf16(af[m], bfr[n], acc[4 + m][n], 0, 0, 0);
    __builtin_amdgcn_s_setprio(0);
    // ---- boundary: counted vmcnt (never 0 in steady state), raw barrier ----
    if (t < NT - 3)       { asm volatile("s_waitcnt vmcnt(8)" ::: "memory"); }
    else if (t == NT - 3) { asm volatile("s_waitcnt vmcnt(4)" ::: "memory"); }
    else if (t == NT - 2) { asm volatile("s_waitcnt vmcnt(0)" ::: "memory"); }
    __builtin_amdgcn_s_barrier();
    __builtin_amdgcn_sched_barrier(0);
  }

  // epilogue: C layout col = lane&15, row = (lane>>4)*4 + reg
  const int rbase = by * 256 + wm * 128 + ((lane >> 4) << 2);
  const int cbase = bx * 256 + wn * 64 + lane15;
#pragma unroll
  for (int n = 0; n < 4; ++n) {
    const int col = cbase + n * 16;
    const float bval = HAS_BIAS ? bias[col] : 0.f;
#pragma unroll
    for (int m = 0; m < 8; ++m) {
#pragma unroll
      for (int r = 0; r < 4; ++r) {
        const int rowg = rbase + m * 16 + r;
        const float v = acc[m][n][r] * scale + bval;
        if (OMODE == 0)
          ((float*)Cv)[(size_t)rowg * N + col] = v;
        else if (OMODE == 1)
          ((u16*)Cv)[(size_t)rowg * N + col] = f2bf(v);
        else  // V-projection: write transposed Vt[b][col][s], b = rowg/2048
          ((u16*)Cv)[(size_t)(rowg >> 11) * ((size_t)DE * SEQ) +
                     (size_t)col * SEQ + (rowg & 2047)] = f2bf(v);
      }
    }
  }
}

// ---------------- m97-style bf16 GEMM (kept for chunked attention GEMMs) ----------------
template <int OMODE, bool HAS_BIAS>
__global__ __launch_bounds__(256) void gemm_tn(
    const u16* __restrict__ A, const u16* __restrict__ Bt, void* __restrict__ Cv,
    const float* __restrict__ bias, int M, int N, int K,
    size_t sA, size_t sB, size_t sC, float scale) {
  __shared__ u16 lA[128 * 64];
  __shared__ u16 lB[128 * 64];
  const int tid = threadIdx.x, lane = tid & 63;
  const int wid = tid >> 6, wr = wid >> 1, wc = wid & 1;

  const int gx = gridDim.x, gy = gridDim.y;
  int lin = blockIdx.x + gx * (blockIdx.y + gy * blockIdx.z);
  const int nwg = gx * gy * (int)gridDim.z;
  const int q = nwg >> 3, r8 = nwg & 7;
  const int xcd = lin & 7, idx = lin >> 3;
  lin = (xcd < r8 ? xcd * (q + 1) : r8 * (q + 1) + (xcd - r8) * q) + idx;
  const int bz = lin / (gx * gy);
  const int rem = lin - bz * (gx * gy);
  const int by = rem / gx, bx = rem - (rem / gx) * gx;

  const char* Ab = (const char*)(A + (size_t)bz * sA + (size_t)by * 128 * K);
  const char* Bb = (const char*)(Bt + (size_t)bz * sB + (size_t)bx * 128 * K);

  const int srow = lane >> 3;
  const int gslot = (lane & 7) ^ srow;
  size_t off[4];
  char* ldsA[4];
  char* ldsB[4];
#pragma unroll
  for (int j = 0; j < 4; ++j) {
    const int row = (wid * 4 + j) * 8 + srow;
    off[j] = (size_t)row * K * 2 + (size_t)gslot * 16;
    ldsA[j] = (char*)lA + (wid * 4 + j) * 1024;
    ldsB[j] = (char*)lB + (wid * 4 + j) * 1024;
  }

  f32x4 acc[4][4] = {};
  const int rfrag = lane & 15;
  const int koff = (lane >> 4) * 8;

  for (int k0 = 0; k0 < K; k0 += 64) {
#pragma unroll
    for (int j = 0; j < 4; ++j) {
      gload16(Ab + off[j], ldsA[j]);
      gload16(Bb + off[j], ldsB[j]);
      off[j] += 128;
    }
    __syncthreads();
#pragma unroll
    for (int kk = 0; kk < 64; kk += 32) {
      bf16x8 af[4], bfr[4];
#pragma unroll
      for (int m = 0; m < 4; ++m) {
        const int r = wr * 64 + m * 16 + rfrag;
        const int slot = ((kk + koff) >> 3) ^ (r & 7);
        af[m] = *(const bf16x8*)((const char*)lA + r * 128 + (slot << 4));
      }
#pragma unroll
      for (int n = 0; n < 4; ++n) {
        const int r = wc * 64 + n * 16 + rfrag;
        const int slot = ((kk + koff) >> 3) ^ (r & 7);
        bfr[n] = *(const bf16x8*)((const char*)lB + r * 128 + (slot << 4));
      }
#pragma unroll
      for (int m = 0; m < 4; ++m)
#pragma unroll
        for (int n = 0; n < 4; ++n)
          acc[m][n] = __builtin_amdgcn_mfma_f32_16x16x32_bf16(af[m], bfr[n], acc[m][n], 0, 0, 0);
    }
    __syncthreads();
  }

  const int rbase = by * 128 + wr * 64 + ((lane >> 4) << 2);
  const int cbase = bx * 128 + wc * 64 + (lane & 15);
#pragma unroll
  for (int m = 0; m < 4; ++m)
#pragma unroll
    for (int n = 0; n < 4; ++n) {
      const int col = cbase + n * 16;
      const float bval = HAS_BIAS ? bias[col] : 0.f;
#pragma unroll
      for (int r = 0; r < 4; ++r) {
        const int rowg = rbase + m * 16 + r;
        const float v = acc[m][n][r] * scale + bval;
        if (OMODE == 0)
          ((float*)Cv)[(size_t)bz * sC + (size_t)rowg * N + col] = v;
        else
          ((u16*)Cv)[(size_t)bz * sC + (size_t)rowg * N + col] = f2bf(v);
      }
    }
}

extern "C" void kernel_launch(void* const* d_in, const int* in_sizes, int n_in,
                              void* d_out, int out_size, void* d_ws, size_t ws_size,
                              hipStream_t stream) {
  const float* x  = (const float*)d_in[0];
  const float* Wq = (const float*)d_in[1];
  const float* bq = (const float*)d_in[2];
  const float* Wk = (const float*)d_in[3];
  const float* bk = (const float*)d_in[4];
  const float* Wv = (const float*)d_in[5];
  const float* bv = (const float*)d_in[6];
  const float* Wo = (const float*)d_in[7];
  const float* bo = (const float*)d_in[8];

  // workspace layout (bytes) — total 159,383,552 (~152 MB)
  const size_t NEED = 159383552;
  if (ws_size < NEED) return;  // fail cleanly instead of page-faulting
  char* ws = (char*)d_ws;
  u16* x_bf = (u16*)(ws);                   // 33,554,432
  u16* q_bf = (u16*)(ws + 33554432);        // 33,554,432
  u16* k_bf = (u16*)(ws + 67108864);        // 33,554,432
  u16* vt   = (u16*)(ws + 100663296);       // 33,554,432  (V^T per batch [d][s])
  u16* wt   = (u16*)(ws + 134217728);       // 8,388,608   (4 x 2MB: q,k,v,o)
  u16* lgP  = (u16*)(ws + 142606336);       // 16,777,216  (2 batches of bf16 logits/P)
  u16* attn = x_bf;                         // alias; x_bf dead after V projection
  u16* wt_q = wt;
  u16* wt_k = wt + 1048576;
  u16* wt_v = wt + 2097152;
  u16* wt_o = wt + 3145728;

  dim3 tb(32, 8);
  const size_t sQ = (size_t)SEQ * DE;   // per-batch Q/K/attn stride
  const size_t sL = (size_t)SEQ * SEQ;  // per-batch logits stride

  // 1. x -> bf16
  cvt_f32_bf16<<<16384, 256, 0, stream>>>(x, x_bf, (NB * SEQ * DIN) / 4);
  // 2. weight transposes (fp32 -> bf16, [K,N] -> [N,K])
  transpose_w<<<dim3(32, 32), tb, 0, stream>>>(Wq, wt_q);
  transpose_w<<<dim3(32, 32), tb, 0, stream>>>(Wk, wt_k);
  transpose_w<<<dim3(32, 32), tb, 0, stream>>>(Wv, wt_v);
  transpose_w<<<dim3(32, 32), tb, 0, stream>>>(Wo, wt_o);
  // 3. QKV projections: [16384,1024] @ [1024,1024]^T + bias (8-phase kernel)
  gemm8p<1, true><<<dim3(4, 64), 512, 0, stream>>>(x_bf, wt_q, q_bf, bq,
      16384, 1024, 1024, 1.f);
  gemm8p<1, true><<<dim3(4, 64), 512, 0, stream>>>(x_bf, wt_k, k_bf, bk,
      16384, 1024, 1024, 1.f);
  gemm8p<2, true><<<dim3(4, 64), 512, 0, stream>>>(x_bf, wt_v, vt, bv,
      16384, 1024, 1024, 1.f);
  // 4. attention in 4 chunks of 2 batches (reuse 16 MB logits buffer)
  for (int c = 0; c < 4; ++c) {
    const u16* qb = q_bf + (size_t)(2 * c) * sQ;
    const u16* kb = k_bf + (size_t)(2 * c) * sQ;
    const u16* vb = vt + (size_t)(2 * c) * sQ;
    u16* ab = attn + (size_t)(2 * c) * sQ;
    // logits = Q @ K^T * (1/32) -> bf16
    gemm_tn<1, false><<<dim3(16, 16, 2), 256, 0, stream>>>(qb, kb, lgP, nullptr,
        2048, 2048, 1024, sQ, sQ, sL, 0.03125f);
    // in-place row softmax
    softmax_rows_bf16<<<2 * SEQ, 256, 0, stream>>>(lgP);
    // values = P @ Vt^T
    gemm_tn<1, false><<<dim3(8, 16, 2), 256, 0, stream>>>(lgP, vb, ab, nullptr,
        2048, 1024, 2048, sL, sQ, sQ, 1.f);
  }
  // 5. out = attn @ Wo + bo (fp32, 8-phase kernel)
  gemm8p<0, true><<<dim3(4, 64), 512, 0, stream>>>(attn, wt_o, d_out, bo,
      16384, 1024, 1024, 1.f);

  (void)in_sizes; (void)n_in; (void)out_size; (void)ws_size;
}

// Round 5
// 369.255 us; speedup vs baseline: 1.4954x; 1.2970x over previous
//
#include <hip/hip_runtime.h>

#define DIN 1024
#define DE  1024
#define SEQ 2048
#define NB  8

typedef __bf16 bf16x8 __attribute__((ext_vector_type(8)));
typedef float  f32x4  __attribute__((ext_vector_type(4)));
typedef unsigned short u16;
typedef u16 u16x8 __attribute__((ext_vector_type(8)));
typedef u16 u16x4 __attribute__((ext_vector_type(4)));

__device__ __forceinline__ u16 f2bf(float f) {
  unsigned u = __builtin_bit_cast(unsigned, f);
  return (u16)((u + 0x7FFFu + ((u >> 16) & 1u)) >> 16);
}
__device__ __forceinline__ float bf2f(u16 h) {
  return __builtin_bit_cast(float, (unsigned)h << 16);
}

typedef __attribute__((address_space(1))) const unsigned char g_u8;
typedef __attribute__((address_space(3))) unsigned char l_u8;
__device__ __forceinline__ void gload16(const void* g, void* l) {
  __builtin_amdgcn_global_load_lds((g_u8*)g, (l_u8*)l, 16, 0, 0);
}

// paired-row swizzle: logical (row r, kslot g in 0..3) -> byte addr in region
__device__ __forceinline__ int swz_addr(int r, int g) {
  return (r >> 1) * 128 + (((((r & 1) << 2) | g) ^ ((r >> 1) & 7)) << 4);
}
// inverse: 16B slot index S -> (row, kslot) it must hold
__device__ __forceinline__ void swz_decode(int S, int& r, int& g) {
  const int pr = S >> 3, phys = S & 7, inner = phys ^ (pr & 7);
  r = pr * 2 + (inner >> 2);
  g = inner & 3;
}

// ---------------- convert fp32 -> bf16 (vectorized) ----------------
__global__ __launch_bounds__(256) void cvt_f32_bf16(const float* __restrict__ in,
                                                    u16* __restrict__ out, int n4) {
  int i = blockIdx.x * 256 + threadIdx.x;
  if (i >= n4) return;
  float4 v = ((const float4*)in)[i];
  u16x4 o;
  o[0] = f2bf(v.x); o[1] = f2bf(v.y); o[2] = f2bf(v.z); o[3] = f2bf(v.w);
  ((u16x4*)out)[i] = o;
}

// ---------------- transpose W [K=1024][N=1024] fp32 -> Wt [N][K] bf16 ----------------
__global__ __launch_bounds__(256) void transpose_w(const float* __restrict__ W,
                                                   u16* __restrict__ Wt) {
  __shared__ float t[32][33];
  const int tx = threadIdx.x, ty = threadIdx.y;
  const int bx = blockIdx.x * 32, by = blockIdx.y * 32;
#pragma unroll
  for (int i = 0; i < 4; ++i)
    t[ty + i * 8][tx] = W[(size_t)(by + ty + i * 8) * 1024 + bx + tx];
  __syncthreads();
#pragma unroll
  for (int i = 0; i < 4; ++i)
    Wt[(size_t)(bx + ty + i * 8) * 1024 + by + tx] = f2bf(t[tx][ty + i * 8]);
}

// ---------------- in-place row softmax on bf16 [rows][2048] ----------------
__global__ __launch_bounds__(256) void softmax_rows_bf16(u16* __restrict__ P) {
  const size_t row = blockIdx.x;
  u16* pr = P + row * 2048 + (size_t)threadIdx.x * 8;
  u16x8 v = *(const u16x8*)pr;
  float x[8];
#pragma unroll
  for (int j = 0; j < 8; ++j) x[j] = bf2f(v[j]);
  float m = x[0];
#pragma unroll
  for (int j = 1; j < 8; ++j) m = fmaxf(m, x[j]);
#pragma unroll
  for (int off = 32; off; off >>= 1) m = fmaxf(m, __shfl_xor(m, off));
  __shared__ float rm[4], rs[4];
  const int lane = threadIdx.x & 63, wid = threadIdx.x >> 6;
  if (lane == 0) rm[wid] = m;
  __syncthreads();
  m = fmaxf(fmaxf(rm[0], rm[1]), fmaxf(rm[2], rm[3]));
  float s = 0.f;
#pragma unroll
  for (int j = 0; j < 8; ++j) { x[j] = __expf(x[j] - m); s += x[j]; }
#pragma unroll
  for (int off = 32; off; off >>= 1) s += __shfl_xor(s, off);
  if (lane == 0) rs[wid] = s;
  __syncthreads();
  s = (rs[0] + rs[1]) + (rs[2] + rs[3]);
  const float inv = 1.f / s;
  u16x8 o;
#pragma unroll
  for (int j = 0; j < 8; ++j) o[j] = f2bf(x[j] * inv);
  *(u16x8*)pr = o;
}

// ============ deep-pipelined GEMM: C = A[M,K] * Bt[N,K]^T (+bias) ============
// Tile BMT x 256, BK=32, quad-buffered LDS, 8 waves, counted vmcnt, paired-row
// XOR swizzle (conflict-free) applied via pre-swizzled global staging source.
// BMT=256: waves 2Mx4N (wave 128x64), 2 phases/tile, 4 loads/tile/thread.
// BMT=128: waves 2Mx4N (wave 64x64), 1 phase/tile, 3 loads/tile/thread.
// OMODE: 0 = fp32 row-major, 1 = bf16 row-major, 2 = bf16 scattered Vt[b][col][s]
template <int BMT, int OMODE, bool HAS_BIAS>
__global__ __launch_bounds__(512, 1) void gemm8p(
    const u16* __restrict__ A, const u16* __restrict__ Bt, void* __restrict__ Cv,
    const float* __restrict__ bias, int M, int N, int K,
    size_t sA, size_t sB, size_t sC, float scale) {
  constexpr int ABYTES = BMT * 64;            // A region bytes per buffer
  constexpr int BUFB = ABYTES + 16384;        // buffer stride
  constexpr int MR = BMT >> 5;                // acc m-frags per wave (8 or 4)
  constexpr int LA = BMT >> 7;                // A loads/thread/tile (2 or 1)
  __shared__ __align__(16) char lds8[4 * BUFB];
  const int tid = threadIdx.x, lane = tid & 63, wid = tid >> 6;
  const int wm = wid >> 2, wn = wid & 3;

  // bijective XCD-aware block remap (3D)
  const int gx = gridDim.x, gy = gridDim.y;
  int lin = blockIdx.x + gx * (blockIdx.y + gy * blockIdx.z);
  const int nwg = gx * gy * (int)gridDim.z;
  const int q = nwg >> 3, r8 = nwg & 7;
  const int xcd = lin & 7, idx = lin >> 3;
  lin = (xcd < r8 ? xcd * (q + 1) : r8 * (q + 1) + (xcd - r8) * q) + idx;
  const int bz = lin / (gx * gy);
  const int rem = lin - bz * (gx * gy);
  const int by = rem / gx, bx = rem - (rem / gx) * gx;

  const char* Ag = (const char*)(A + (size_t)bz * sA + (size_t)by * BMT * K);
  const char* Bg = (const char*)(Bt + (size_t)bz * sB + (size_t)bx * 256 * K);
  const size_t Kb = (size_t)K * 2;

  // staging: load j covers slots [(j*8+wid)*64, +64); lane l -> slot base+l.
  // source (row, kslot) from swz_decode so linear LDS holds the swizzled layout.
  const char* srcA[2];
  const char* srcB[2];
  char* dstA[2];
  char* dstB[2];
#pragma unroll
  for (int j = 0; j < LA; ++j) {
    int S = (j * 8 + wid) * 64 + lane, r, g;
    swz_decode(S, r, g);
    srcA[j] = Ag + (size_t)r * Kb + g * 16;
    dstA[j] = lds8 + (j * 8 + wid) * 1024;
  }
#pragma unroll
  for (int j = 0; j < 2; ++j) {
    int S = (j * 8 + wid) * 64 + lane, r, g;
    swz_decode(S, r, g);
    srcB[j] = Bg + (size_t)r * Kb + g * 16;
    dstB[j] = lds8 + ABYTES + (j * 8 + wid) * 1024;
  }

  // fragment read byte-offsets within a buffer
  const int lane15 = lane & 15, gk = lane >> 4;
  int aoff[MR], boff[4];
#pragma unroll
  for (int m = 0; m < MR; ++m)
    aoff[m] = swz_addr(wm * (BMT / 2) + m * 16 + lane15, gk);
#pragma unroll
  for (int n = 0; n < 4; ++n)
    boff[n] = ABYTES + swz_addr(wn * 64 + n * 16 + lane15, gk);

  f32x4 acc[MR][4] = {};
  const int NT = K >> 5;

  // prologue: stage tiles 0..2, wait for tile 0
#pragma unroll
  for (int pt = 0; pt < 3; ++pt) {
    const int bb = pt * BUFB;
#pragma unroll
    for (int j = 0; j < LA; ++j) { gload16(srcA[j], dstA[j] + bb); srcA[j] += 64; }
#pragma unroll
    for (int j = 0; j < 2; ++j) { gload16(srcB[j], dstB[j] + bb); srcB[j] += 64; }
  }
  if constexpr (BMT == 256) asm volatile("s_waitcnt vmcnt(8)" ::: "memory");
  else                      asm volatile("s_waitcnt vmcnt(6)" ::: "memory");
  __builtin_amdgcn_s_barrier();
  __builtin_amdgcn_sched_barrier(0);

  for (int t = 0; t < NT; ++t) {
    const char* base = lds8 + (t & 3) * BUFB;
    const int dbb = ((t + 3) & 3) * BUFB;
    const bool st = (t + 3) < NT;
    bf16x8 af[4], bfr[4];
#pragma unroll
    for (int n = 0; n < 4; ++n) bfr[n] = *(const bf16x8*)(base + boff[n]);
#pragma unroll
    for (int m = 0; m < 4; ++m) af[m] = *(const bf16x8*)(base + aoff[m]);
    if constexpr (BMT == 256) {
      // ---- phase 0: m-half 0, stage A of tile t+3 ----
      if (st) {
        gload16(srcA[0], dstA[0] + dbb); srcA[0] += 64;
        gload16(srcA[1], dstA[1] + dbb); srcA[1] += 64;
      }
      __builtin_amdgcn_s_setprio(1);
#pragma unroll
      for (int m = 0; m < 4; ++m)
#pragma unroll
        for (int n = 0; n < 4; ++n)
          acc[m][n] = __builtin_amdgcn_mfma_f32_16x16x32_bf16(af[m], bfr[n], acc[m][n], 0, 0, 0);
      __builtin_amdgcn_s_setprio(0);
      __builtin_amdgcn_s_barrier();
      // ---- phase 1: m-half 1, stage B of tile t+3 ----
#pragma unroll
      for (int m = 0; m < 4; ++m) af[m] = *(const bf16x8*)(base + aoff[4 + m]);
      if (st) {
        gload16(srcB[0], dstB[0] + dbb); srcB[0] += 64;
        gload16(srcB[1], dstB[1] + dbb); srcB[1] += 64;
      }
      __builtin_amdgcn_s_setprio(1);
#pragma unroll
      for (int m = 0; m < 4; ++m)
#pragma unroll
        for (int n = 0; n < 4; ++n)
          acc[4 + m][n] = __builtin_amdgcn_mfma_f32_16x16x32_bf16(af[m], bfr[n], acc[4 + m][n], 0, 0, 0);
      __builtin_amdgcn_s_setprio(0);
      if (t < NT - 3)       asm volatile("s_waitcnt vmcnt(8)" ::: "memory");
      else if (t == NT - 3) asm volatile("s_waitcnt vmcnt(4)" ::: "memory");
      else if (t == NT - 2) asm volatile("s_waitcnt vmcnt(0)" ::: "memory");
    } else {
      // ---- single phase: stage A+B of tile t+3 ----
      if (st) {
        gload16(srcA[0], dstA[0] + dbb); srcA[0] += 64;
        gload16(srcB[0], dstB[0] + dbb); srcB[0] += 64;
        gload16(srcB[1], dstB[1] + dbb); srcB[1] += 64;
      }
      __builtin_amdgcn_s_setprio(1);
#pragma unroll
      for (int m = 0; m < 4; ++m)
#pragma unroll
        for (int n = 0; n < 4; ++n)
          acc[m][n] = __builtin_amdgcn_mfma_f32_16x16x32_bf16(af[m], bfr[n], acc[m][n], 0, 0, 0);
      __builtin_amdgcn_s_setprio(0);
      if (t < NT - 3)       asm volatile("s_waitcnt vmcnt(6)" ::: "memory");
      else if (t == NT - 3) asm volatile("s_waitcnt vmcnt(3)" ::: "memory");
      else if (t == NT - 2) asm volatile("s_waitcnt vmcnt(0)" ::: "memory");
    }
    __builtin_amdgcn_s_barrier();
    __builtin_amdgcn_sched_barrier(0);
  }

  // epilogue: C layout col = lane&15, row = (lane>>4)*4 + reg
  const int rbase = by * BMT + wm * (BMT / 2) + ((lane >> 4) << 2);
  const int cbase = bx * 256 + wn * 64 + lane15;
#pragma unroll
  for (int m = 0; m < MR; ++m)
#pragma unroll
    for (int n = 0; n < 4; ++n) {
      const int col = cbase + n * 16;
      const float bval = HAS_BIAS ? bias[col] : 0.f;
#pragma unroll
      for (int r = 0; r < 4; ++r) {
        const int rowg = rbase + m * 16 + r;
        const float v = acc[m][n][r] * scale + bval;
        if (OMODE == 0)
          ((float*)Cv)[(size_t)bz * sC + (size_t)rowg * N + col] = v;
        else if (OMODE == 1)
          ((u16*)Cv)[(size_t)bz * sC + (size_t)rowg * N + col] = f2bf(v);
        else  // V-projection: write transposed Vt[b][col][s], b = rowg/2048
          ((u16*)Cv)[(size_t)(rowg >> 11) * ((size_t)DE * SEQ) +
                     (size_t)col * SEQ + (rowg & 2047)] = f2bf(v);
      }
    }
}

extern "C" void kernel_launch(void* const* d_in, const int* in_sizes, int n_in,
                              void* d_out, int out_size, void* d_ws, size_t ws_size,
                              hipStream_t stream) {
  const float* x  = (const float*)d_in[0];
  const float* Wq = (const float*)d_in[1];
  const float* bq = (const float*)d_in[2];
  const float* Wk = (const float*)d_in[3];
  const float* bk = (const float*)d_in[4];
  const float* Wv = (const float*)d_in[5];
  const float* bv = (const float*)d_in[6];
  const float* Wo = (const float*)d_in[7];
  const float* bo = (const float*)d_in[8];

  // workspace layout (bytes) — total 150,994,944 (~144 MB)
  const size_t NEED = 150994944;
  if (ws_size < NEED) return;  // fail cleanly instead of page-faulting
  char* ws = (char*)d_ws;
  u16* x_bf = (u16*)(ws);                   // 33,554,432 (x; later lgP per chunk)
  u16* q_bf = (u16*)(ws + 33554432);        // 33,554,432 (Q; later attn output)
  u16* k_bf = (u16*)(ws + 67108864);        // 33,554,432
  u16* vt   = (u16*)(ws + 100663296);       // 33,554,432 (V^T per batch [d][s])
  u16* wt   = (u16*)(ws + 134217728);       // 8,388,608  (4 x 2MB: q,k,v,o)
  u16* lgP  = x_bf;                         // alias: [8][1024][2048] bf16 per chunk
  u16* wt_q = wt;
  u16* wt_k = wt + 1048576;
  u16* wt_v = wt + 2097152;
  u16* wt_o = wt + 3145728;

  dim3 tb(32, 8);
  const size_t sQ = (size_t)SEQ * DE;   // 2,097,152: per-batch Q/K/attn/vt stride
  const size_t sL = (size_t)1024 * SEQ; // 2,097,152: per-batch chunk-logits stride

  // 1. x -> bf16
  cvt_f32_bf16<<<16384, 256, 0, stream>>>(x, x_bf, (NB * SEQ * DIN) / 4);
  // 2. weight transposes (fp32 -> bf16, [K,N] -> [N,K])
  transpose_w<<<dim3(32, 32), tb, 0, stream>>>(Wq, wt_q);
  transpose_w<<<dim3(32, 32), tb, 0, stream>>>(Wk, wt_k);
  transpose_w<<<dim3(32, 32), tb, 0, stream>>>(Wv, wt_v);
  transpose_w<<<dim3(32, 32), tb, 0, stream>>>(Wo, wt_o);
  // 3. QKV projections: [16384,1024] @ [1024,1024]^T + bias
  gemm8p<256, 1, true><<<dim3(4, 64, 1), 512, 0, stream>>>(x_bf, wt_q, q_bf, bq,
      16384, 1024, 1024, 0, 0, 0, 1.f);
  gemm8p<256, 1, true><<<dim3(4, 64, 1), 512, 0, stream>>>(x_bf, wt_k, k_bf, bk,
      16384, 1024, 1024, 0, 0, 0, 1.f);
  gemm8p<256, 2, true><<<dim3(4, 64, 1), 512, 0, stream>>>(x_bf, wt_v, vt, bv,
      16384, 1024, 1024, 0, 0, 0, 1.f);
  // 4. attention in 2 M-chunks of 1024 Q-rows x all 8 batches
  for (int c = 0; c < 2; ++c) {
    const u16* qc = q_bf + (size_t)c * 1048576;  // rows [1024c, 1024c+1024) per batch
    // logits = Qc @ K^T * (1/32) -> lgP [8][1024][2048] bf16
    gemm8p<128, 1, false><<<dim3(8, 8, 8), 512, 0, stream>>>(qc, k_bf, lgP, nullptr,
        1024, 2048, 1024, sQ, sQ, sL, 0.03125f);
    // in-place row softmax (8*1024 rows)
    softmax_rows_bf16<<<8192, 256, 0, stream>>>(lgP);
    // values = P @ Vt^T -> overwrite the just-consumed Q stripes
    gemm8p<128, 1, false><<<dim3(4, 8, 8), 512, 0, stream>>>(lgP, vt,
        q_bf + (size_t)c * 1048576, nullptr, 1024, 1024, 2048, sL, sQ, sQ, 1.f);
  }
  // 5. out = attn @ Wo + bo (fp32)
  gemm8p<256, 0, true><<<dim3(4, 64, 1), 512, 0, stream>>>(q_bf, wt_o, d_out, bo,
      16384, 1024, 1024, 0, 0, 0, 1.f);

  (void)in_sizes; (void)n_in; (void)out_size; (void)ws_size;
}